// Round 7
// baseline (246.036 us; speedup 1.0000x reference)
//
#include <hip/hip_runtime.h>
#include <hip/hip_bf16.h>

typedef __bf16 bf16;
typedef __attribute__((ext_vector_type(8))) __bf16 bf16x8;
typedef __attribute__((ext_vector_type(4))) float f32x4;

#define T_SEQ 4096
#define D_EMB 1024
#define HS 64

__device__ __forceinline__ float fexp2(float x) {
#if __has_builtin(__builtin_amdgcn_exp2f)
    return __builtin_amdgcn_exp2f(x);
#else
    return exp2f(x);
#endif
}

// ---------------------------------------------------------------------------
// Kernel 0: cast Wk|Wv (fp32, 64x1024 each) -> bf16 workspace copies.
// ---------------------------------------------------------------------------
__global__ __launch_bounds__(256) void wcast_kernel(
    const float* __restrict__ Wk, const float* __restrict__ Wv,
    bf16* __restrict__ wbf)   // [128][1024]
{
    const int t = blockIdx.x * 256 + threadIdx.x;
    const int base = t * 8;
    const float* src = (base < 65536) ? (Wk + base) : (Wv + base - 65536);
    float4 f0 = *(const float4*)(src);
    float4 f1 = *(const float4*)(src + 4);
    bf16x8 o = {(__bf16)f0.x, (__bf16)f0.y, (__bf16)f0.z, (__bf16)f0.w,
                (__bf16)f1.x, (__bf16)f1.y, (__bf16)f1.z, (__bf16)f1.w};
    *(bf16x8*)(wbf + base) = o;
}

// ---------------------------------------------------------------------------
// Kernel 1: projection GEMM, K-split x4 (unchanged; ~HBM floor on x).
// ---------------------------------------------------------------------------
__global__ __launch_bounds__(256) void proj_kernel(
    const float* __restrict__ x,    // [16384][1024] fp32
    const bf16* __restrict__ wbf,   // [128][1024] bf16
    bf16* __restrict__ kmat,        // [16384][64]
    bf16* __restrict__ qvmat,       // [16384][64]
    bf16* __restrict__ qvT)         // [4][64][4096]
{
    __shared__ float red[4][2048];   // 32 KB

    const int lane = threadIdx.x & 63;
    const int wave = threadIdx.x >> 6;
    const int col  = lane & 15;
    const int quad = lane >> 4;
    const int rowbase = blockIdx.x * 16;

    const float* xrow = x + (size_t)(rowbase + col) * D_EMB + wave * 256;

    f32x4 acc[8];
#pragma unroll
    for (int i = 0; i < 8; ++i) acc[i] = {0.f, 0.f, 0.f, 0.f};

    for (int k0 = 0; k0 < 256; k0 += 32) {
        float4 a0 = *(const float4*)(xrow + k0 + quad * 8);
        float4 a1 = *(const float4*)(xrow + k0 + quad * 8 + 4);
        bf16x8 a = {(__bf16)a0.x, (__bf16)a0.y, (__bf16)a0.z, (__bf16)a0.w,
                    (__bf16)a1.x, (__bf16)a1.y, (__bf16)a1.z, (__bf16)a1.w};
#pragma unroll
        for (int nt = 0; nt < 8; ++nt) {
            const bf16* wrow = wbf + (size_t)(nt * 16 + col) * D_EMB + wave * 256;
            bf16x8 b = *(const bf16x8*)(wrow + k0 + quad * 8);
            acc[nt] = __builtin_amdgcn_mfma_f32_16x16x32_bf16(a, b, acc[nt], 0, 0, 0);
        }
    }

#pragma unroll
    for (int nt = 0; nt < 8; ++nt)
        *(f32x4*)&red[wave][nt * 256 + lane * 4] = acc[nt];
    __syncthreads();

    const int t = threadIdx.x;
    f32x4 s0 = {0.f,0.f,0.f,0.f}, s1 = {0.f,0.f,0.f,0.f};
#pragma unroll
    for (int w = 0; w < 4; ++w) {
        s0 += *(const f32x4*)&red[w][t * 8];
        s1 += *(const f32x4*)&red[w][t * 8 + 4];
    }
    const int nt = t >> 5;
    const int L0 = (t & 31) * 2;
#pragma unroll
    for (int j2 = 0; j2 < 2; ++j2) {
        const int L  = L0 + j2;
        const int q  = L >> 4;
        const int cc = L & 15;
        const int c  = (nt & 3) * 16 + cc;
        f32x4 v = j2 ? s1 : s0;
#pragma unroll
        for (int r = 0; r < 4; ++r) {
            const int grow = rowbase + q * 4 + r;
            bf16 bv = (bf16)v[r];
            if (nt < 4) {
                kmat[(size_t)grow * HS + c] = bv;
            } else {
                qvmat[(size_t)grow * HS + c] = bv;
                const int bb = grow >> 12;
                const int tt = grow & (T_SEQ - 1);
                qvT[((size_t)bb * HS + c) * T_SEQ + tt] = bv;
            }
        }
    }
}

// ---------------------------------------------------------------------------
// Kernel 2: causal attention, fixed-offset softmax, q = v.
// Job = (batch, 64-row q-block, 32-tile key chunk). Grid 1024 (c >= nc blocks
// exit uniformly; ~640 working). bid scrambled (*421 mod 1024) for CU balance.
// All 4 waves of a block walk the SAME key tiles (wave owns 16 of the 64 Q
// rows) -> identical global addresses across waves -> L1/MSHR merge, ~4x less
// miss traffic than round-robin tile split. Partial (O raw, l) written per
// chunk (slot 0 = out itself); norm kernel combines.
// ---------------------------------------------------------------------------
__global__ __launch_bounds__(256) void attn_kernel(
    const bf16* __restrict__ kmat,   // [B*T][64]
    const bf16* __restrict__ qvmat,  // [B*T][64]
    const bf16* __restrict__ qvT,    // [B][64][T]
    float* __restrict__ out,         // [B*T][64] raw O partial, chunk 0
    float* __restrict__ o_parts,     // [3][B*T][64] raw O partials, chunks 1-3
    float* __restrict__ l_parts)     // [4][B*T] l partials
{
    __shared__ bf16 plds[4][16][40];   // P roundtrip, 5 KB

    const int lane = threadIdx.x & 63;
    const int wave = threadIdx.x >> 6;
    const int col  = lane & 15;
    const int quad = lane >> 4;

    const int bid = (blockIdx.x * 421) & 1023;   // scramble: decorrelate CU<->work
    const int b   = bid >> 8;
    const int rem = bid & 255;
    const int qb  = rem & 63;
    const int c   = rem >> 6;
    const int nc  = (qb >> 4) + 1;        // chunks for this q-block
    if (c >= nc) return;                  // block-uniform exit

    const int nk   = 2 * qb + 2;          // key tiles for the 64-row block
    const int tbeg = c * 32;
    const int tend = (nk < tbeg + 32) ? nk : tbeg + 32;

    const int q0  = qb * 64 + wave * 16;             // this wave's first row
    const int nkw = 2 * qb + 1 + (wave >> 1);        // wave's causal tile limit
    const int wend = (tend < nkw) ? tend : nkw;

    const bf16* qvb = qvmat + (size_t)b * T_SEQ * HS;
    const bf16* kb  = kmat  + (size_t)b * T_SEQ * HS;
    const bf16* vTb = qvT   + (size_t)b * HS * T_SEQ;

    bf16x8 qf0 = *(const bf16x8*)(qvb + (size_t)(q0 + col) * HS + quad * 8);
    bf16x8 qf1 = *(const bf16x8*)(qvb + (size_t)(q0 + col) * HS + 32 + quad * 8);

    f32x4 o[4];
    float lp[4];
#pragma unroll
    for (int h = 0; h < 4; ++h) o[h] = {0.f, 0.f, 0.f, 0.f};
#pragma unroll
    for (int r = 0; r < 4; ++r) lp[r] = 0.f;

    const float sc = 0.125f * 1.44269504088896f;

#pragma unroll 1
    for (int t = tbeg; t < wend; ++t) {
        const int s0 = t * 32;

        // ---- loads: same addresses across all 4 waves of the block ----
        const bf16* kr0 = kb + (size_t)(s0 + col) * HS;
        const bf16* kr1 = kb + (size_t)(s0 + 16 + col) * HS;
        bf16x8 k0 = *(const bf16x8*)(kr0 + quad * 8);
        bf16x8 k1 = *(const bf16x8*)(kr0 + 32 + quad * 8);
        bf16x8 k2 = *(const bf16x8*)(kr1 + quad * 8);
        bf16x8 k3 = *(const bf16x8*)(kr1 + 32 + quad * 8);
        bf16x8 vc[4];
#pragma unroll
        for (int h = 0; h < 4; ++h)
            vc[h] = *(const bf16x8*)(vTb + (size_t)(h * 16 + col) * T_SEQ + s0 + quad * 8);

        // ---- S = Q K^T, p = exp2(S*sc - 24) ----
        float p[2][4];
        {
            f32x4 a4 = {0.f, 0.f, 0.f, 0.f};
            a4 = __builtin_amdgcn_mfma_f32_16x16x32_bf16(qf0, k0, a4, 0, 0, 0);
            a4 = __builtin_amdgcn_mfma_f32_16x16x32_bf16(qf1, k1, a4, 0, 0, 0);
#pragma unroll
            for (int r = 0; r < 4; ++r)
                p[0][r] = fexp2(fmaf(a4[r], sc, -24.f));
        }
        {
            f32x4 a4 = {0.f, 0.f, 0.f, 0.f};
            a4 = __builtin_amdgcn_mfma_f32_16x16x32_bf16(qf0, k2, a4, 0, 0, 0);
            a4 = __builtin_amdgcn_mfma_f32_16x16x32_bf16(qf1, k3, a4, 0, 0, 0);
#pragma unroll
            for (int r = 0; r < 4; ++r)
                p[1][r] = fexp2(fmaf(a4[r], sc, -24.f));
        }

        if (s0 + 31 > q0) {   // diagonal tile for this wave: zero masked probs
#pragma unroll
            for (int ntile = 0; ntile < 2; ++ntile)
#pragma unroll
                for (int r = 0; r < 4; ++r)
                    if (s0 + ntile * 16 + col > q0 + quad * 4 + r)
                        p[ntile][r] = 0.f;
        }

#pragma unroll
        for (int r = 0; r < 4; ++r) lp[r] += p[0][r] + p[1][r];

        // ---- P: C-layout -> LDS -> A-layout (wave-private, in-order DS) ----
#pragma unroll
        for (int ntile = 0; ntile < 2; ++ntile)
#pragma unroll
            for (int r = 0; r < 4; ++r)
                plds[wave][quad * 4 + r][ntile * 16 + col] = (bf16)p[ntile][r];
        bf16x8 pa = *(const bf16x8*)&plds[wave][col][quad * 8];

        // ---- O += P V ----
#pragma unroll
        for (int h = 0; h < 4; ++h)
            o[h] = __builtin_amdgcn_mfma_f32_16x16x32_bf16(pa, vc[h], o[h], 0, 0, 0);
    }

    // ---- epilogue: waves own disjoint rows -> direct partial stores ----
    float lr[4];
#pragma unroll
    for (int r = 0; r < 4; ++r) {
        float v = lp[r];
#pragma unroll
        for (int off = 1; off < 16; off <<= 1)
            v += __shfl_xor(v, off, 64);
        lr[r] = v;   // every lane of the quad group has the row sum
    }

    const size_t rowbase = (size_t)b * T_SEQ + q0 + quad * 4;
    if (col == 0) {
#pragma unroll
        for (int r = 0; r < 4; ++r)
            l_parts[(size_t)c * 16384 + rowbase + r] = lr[r];
    }

    float* dst = (c == 0) ? out : (o_parts + (size_t)(c - 1) * 16384 * HS);
#pragma unroll
    for (int h = 0; h < 4; ++h)
#pragma unroll
        for (int r = 0; r < 4; ++r)
            dst[(rowbase + r) * HS + h * 16 + col] = o[h][r];
}

// ---------------------------------------------------------------------------
// Kernel 3: combine chunk partials and normalize: out = sum(O_c) / sum(l_c).
// ---------------------------------------------------------------------------
__global__ __launch_bounds__(256) void norm_kernel(
    float* __restrict__ out,            // in/out: slot-0 raw -> final
    const float* __restrict__ o_parts,  // [3][B*T][64]
    const float* __restrict__ l_parts)  // [4][B*T]
{
    const int i   = blockIdx.x * 256 + threadIdx.x;   // 0 .. 1048575
    const int row = i >> 6;
    const int qb  = (row & 4095) >> 6;
    const int nc  = (qb >> 4) + 1;      // wave-uniform (64 consecutive i = 1 row)

    float s = out[i];
    float L = l_parts[row];
    for (int c = 1; c < nc; ++c) {
        s += o_parts[(size_t)(c - 1) * 1048576 + i];
        L += l_parts[(size_t)c * 16384 + row];
    }
    out[i] = s / L;
}

extern "C" void kernel_launch(void* const* d_in, const int* in_sizes, int n_in,
                              void* d_out, int out_size, void* d_ws, size_t ws_size,
                              hipStream_t stream) {
    const float* x  = (const float*)d_in[0];
    const float* Wk = (const float*)d_in[1];
    const float* Wv = (const float*)d_in[2];
    float* out = (float*)d_out;

    bf16* ws    = (bf16*)d_ws;
    bf16* wbf   = ws;                                    // 256 KB
    bf16* kmat  = ws + (size_t)128 * 1024;               // 2 MB
    bf16* qvmat = kmat + (size_t)16384 * 64;             // 2 MB
    bf16* qvT   = qvmat + (size_t)16384 * 64;            // 2 MB
    float* o_parts = (float*)(qvT + (size_t)16384 * 64); // 12 MB (chunks 1-3)
    float* l_parts = o_parts + (size_t)3 * 16384 * 64;   // 256 KB

    wcast_kernel<<<64, 256, 0, stream>>>(Wk, Wv, wbf);
    proj_kernel<<<1024, 256, 0, stream>>>(x, wbf, kmat, qvmat, qvT);
    attn_kernel<<<1024, 256, 0, stream>>>(kmat, qvmat, qvT, out, o_parts, l_parts);
    norm_kernel<<<4096, 256, 0, stream>>>(out, o_parts, l_parts);
}

// Round 8
// 165.093 us; speedup vs baseline: 1.4903x; 1.4903x over previous
//
#include <hip/hip_runtime.h>
#include <hip/hip_bf16.h>

typedef __bf16 bf16;
typedef __attribute__((ext_vector_type(8))) __bf16 bf16x8;
typedef __attribute__((ext_vector_type(4))) float f32x4;

#define T_SEQ 4096
#define D_EMB 1024
#define HS 64

__device__ __forceinline__ float fexp2(float x) {
#if __has_builtin(__builtin_amdgcn_exp2f)
    return __builtin_amdgcn_exp2f(x);
#else
    return exp2f(x);
#endif
}

// ---------------------------------------------------------------------------
// Kernel 0: cast Wk|Wv (fp32, 64x1024 each) -> bf16 workspace copies.
// ---------------------------------------------------------------------------
__global__ __launch_bounds__(256) void wcast_kernel(
    const float* __restrict__ Wk, const float* __restrict__ Wv,
    bf16* __restrict__ wbf)   // [128][1024]
{
    const int t = blockIdx.x * 256 + threadIdx.x;
    const int base = t * 8;
    const float* src = (base < 65536) ? (Wk + base) : (Wv + base - 65536);
    float4 f0 = *(const float4*)(src);
    float4 f1 = *(const float4*)(src + 4);
    bf16x8 o = {(__bf16)f0.x, (__bf16)f0.y, (__bf16)f0.z, (__bf16)f0.w,
                (__bf16)f1.x, (__bf16)f1.y, (__bf16)f1.z, (__bf16)f1.w};
    *(bf16x8*)(wbf + base) = o;
}

// ---------------------------------------------------------------------------
// Kernel 1: projection GEMM, K-split x4 (unchanged this round).
// ---------------------------------------------------------------------------
__global__ __launch_bounds__(256) void proj_kernel(
    const float* __restrict__ x,    // [16384][1024] fp32
    const bf16* __restrict__ wbf,   // [128][1024] bf16
    bf16* __restrict__ kmat,        // [16384][64]
    bf16* __restrict__ qvmat,       // [16384][64]
    bf16* __restrict__ qvT)         // [4][64][4096]
{
    __shared__ float red[4][2048];   // 32 KB

    const int lane = threadIdx.x & 63;
    const int wave = threadIdx.x >> 6;
    const int col  = lane & 15;
    const int quad = lane >> 4;
    const int rowbase = blockIdx.x * 16;

    const float* xrow = x + (size_t)(rowbase + col) * D_EMB + wave * 256;

    f32x4 acc[8];
#pragma unroll
    for (int i = 0; i < 8; ++i) acc[i] = {0.f, 0.f, 0.f, 0.f};

    for (int k0 = 0; k0 < 256; k0 += 32) {
        float4 a0 = *(const float4*)(xrow + k0 + quad * 8);
        float4 a1 = *(const float4*)(xrow + k0 + quad * 8 + 4);
        bf16x8 a = {(__bf16)a0.x, (__bf16)a0.y, (__bf16)a0.z, (__bf16)a0.w,
                    (__bf16)a1.x, (__bf16)a1.y, (__bf16)a1.z, (__bf16)a1.w};
#pragma unroll
        for (int nt = 0; nt < 8; ++nt) {
            const bf16* wrow = wbf + (size_t)(nt * 16 + col) * D_EMB + wave * 256;
            bf16x8 b = *(const bf16x8*)(wrow + k0 + quad * 8);
            acc[nt] = __builtin_amdgcn_mfma_f32_16x16x32_bf16(a, b, acc[nt], 0, 0, 0);
        }
    }

#pragma unroll
    for (int nt = 0; nt < 8; ++nt)
        *(f32x4*)&red[wave][nt * 256 + lane * 4] = acc[nt];
    __syncthreads();

    const int t = threadIdx.x;
    f32x4 s0 = {0.f,0.f,0.f,0.f}, s1 = {0.f,0.f,0.f,0.f};
#pragma unroll
    for (int w = 0; w < 4; ++w) {
        s0 += *(const f32x4*)&red[w][t * 8];
        s1 += *(const f32x4*)&red[w][t * 8 + 4];
    }
    const int nt = t >> 5;
    const int L0 = (t & 31) * 2;
#pragma unroll
    for (int j2 = 0; j2 < 2; ++j2) {
        const int L  = L0 + j2;
        const int q  = L >> 4;
        const int cc = L & 15;
        const int c  = (nt & 3) * 16 + cc;
        f32x4 v = j2 ? s1 : s0;
#pragma unroll
        for (int r = 0; r < 4; ++r) {
            const int grow = rowbase + q * 4 + r;
            bf16 bv = (bf16)v[r];
            if (nt < 4) {
                kmat[(size_t)grow * HS + c] = bv;
            } else {
                qvmat[(size_t)grow * HS + c] = bv;
                const int bb = grow >> 12;
                const int tt = grow & (T_SEQ - 1);
                qvT[((size_t)bb * HS + c) * T_SEQ + tt] = bv;
            }
        }
    }
}

// ---------------------------------------------------------------------------
// Kernel 2: staged-LDS causal attention, fixed-offset softmax, q = v.
// Job = (batch, 64-row q-block qb, 8-chunk range jc); 1152 jobs total.
// Per 64-key chunk the block stages K (8 KB contiguous) and V^T (64 rows x
// 128 B from qvT) into padded LDS with 16 coalesced wave-loads, double-
// buffered. All MFMA B-fragments are ds_read_b128 (<=2-way bank alias, free).
// Waves own disjoint 16-row groups; partial (O, l) stored to per-job slot.
// ---------------------------------------------------------------------------
__global__ __launch_bounds__(256, 3) void attn_kernel(
    const bf16* __restrict__ kmat,   // [B*T][64]
    const bf16* __restrict__ qvmat,  // [B*T][64]
    const bf16* __restrict__ qvT,    // [B][64][T]
    float* __restrict__ out,         // [B*T][64] raw O partial, slot 0
    float* __restrict__ o_parts,     // [7][B*T][64] raw O partials, slots 1-7
    float* __restrict__ l_parts)     // [8][B*T] l partials
{
    __shared__ bf16 Kt[2][64][72];   // 18.4 KB, rows padded to 144 B
    __shared__ bf16 Vt[2][64][72];   // 18.4 KB
    __shared__ bf16 plds[4][16][40]; // 5 KB P roundtrip

    const int tid  = threadIdx.x;
    const int lane = tid & 63;
    const int wave = tid >> 6;
    const int col  = lane & 15;
    const int quad = lane >> 4;

    // ---- job decode: 288 jobs/batch; tier a has q-blocks 8a..8a+7, a+1 jobs each
    const int b = blockIdx.x / 288;
    const int r = blockIdx.x - b * 288;
    int a = 0;
    while (4 * (a + 1) * (a + 2) <= r) ++a;          // a in 0..7
    const int rr = r - 4 * a * (a + 1);
    const int m  = rr / (a + 1);
    const int jc = rr - m * (a + 1);                 // job slot 0..a
    const int qb = 8 * a + m;                        // q-block 0..63

    const int cbeg  = jc * 8;
    const int nctot = qb + 1;                        // causal chunk count
    const int cend  = (nctot < cbeg + 8) ? nctot : cbeg + 8;

    const bf16* qvb = qvmat + (size_t)b * T_SEQ * HS;
    const bf16* kb  = kmat  + (size_t)b * T_SEQ * HS;
    const bf16* vTb = qvT   + (size_t)b * HS * T_SEQ;

    const int q0 = qb * 64 + wave * 16;              // wave's first q-row

    bf16x8 qf0 = *(const bf16x8*)(qvb + (size_t)(q0 + col) * HS + quad * 8);
    bf16x8 qf1 = *(const bf16x8*)(qvb + (size_t)(q0 + col) * HS + 32 + quad * 8);

    f32x4 o[4];
    float lp[4];
#pragma unroll
    for (int h = 0; h < 4; ++h) o[h] = {0.f, 0.f, 0.f, 0.f};
#pragma unroll
    for (int rr2 = 0; rr2 < 4; ++rr2) lp[rr2] = 0.f;

    const float sc = 0.125f * 1.44269504088896f;

    // ---- stage first chunk into buffer 0 ----
    {
        const int kc = cbeg * 64;
#pragma unroll
        for (int it = 0; it < 2; ++it) {
            const int idx = it * 256 + tid;          // 0..511
            const int kr  = idx >> 3;
            const int off = (idx & 7) * 8;
            bf16x8 kv = *(const bf16x8*)(kb + (size_t)kc * HS + idx * 8);
            bf16x8 vv = *(const bf16x8*)(vTb + (size_t)kr * T_SEQ + kc + off);
            *(bf16x8*)&Kt[0][kr][off] = kv;
            *(bf16x8*)&Vt[0][kr][off] = vv;
        }
    }
    __syncthreads();

    int buf = 0;
#pragma unroll 1
    for (int c = cbeg; c < cend; ++c) {
        const bool more = (c + 1 < cend);

        // ---- prefetch next chunk into registers (coalesced) ----
        bf16x8 kn[2], vn[2];
        if (more) {
            const int kcn = (c + 1) * 64;
#pragma unroll
            for (int it = 0; it < 2; ++it) {
                const int idx = it * 256 + tid;
                const int kr  = idx >> 3;
                const int off = (idx & 7) * 8;
                kn[it] = *(const bf16x8*)(kb + (size_t)kcn * HS + idx * 8);
                vn[it] = *(const bf16x8*)(vTb + (size_t)kr * T_SEQ + kcn + off);
            }
        }

        // ---- compute chunk c from LDS ----
        const int kc = c * 64;
#pragma unroll
        for (int st = 0; st < 2; ++st) {
            const int gk = kc + 32 * st;             // subtile's first key
            if (gk > q0 + 15) break;                 // fully masked (wave-uniform)

            bf16x8 b0 = *(const bf16x8*)&Kt[buf][32 * st + col][quad * 8];
            bf16x8 b1 = *(const bf16x8*)&Kt[buf][32 * st + col][32 + quad * 8];
            bf16x8 b2 = *(const bf16x8*)&Kt[buf][32 * st + 16 + col][quad * 8];
            bf16x8 b3 = *(const bf16x8*)&Kt[buf][32 * st + 16 + col][32 + quad * 8];

            float p[2][4];
            {
                f32x4 a4 = {0.f, 0.f, 0.f, 0.f};
                a4 = __builtin_amdgcn_mfma_f32_16x16x32_bf16(qf0, b0, a4, 0, 0, 0);
                a4 = __builtin_amdgcn_mfma_f32_16x16x32_bf16(qf1, b1, a4, 0, 0, 0);
#pragma unroll
                for (int i = 0; i < 4; ++i) p[0][i] = fexp2(fmaf(a4[i], sc, -24.f));
            }
            {
                f32x4 a4 = {0.f, 0.f, 0.f, 0.f};
                a4 = __builtin_amdgcn_mfma_f32_16x16x32_bf16(qf0, b2, a4, 0, 0, 0);
                a4 = __builtin_amdgcn_mfma_f32_16x16x32_bf16(qf1, b3, a4, 0, 0, 0);
#pragma unroll
                for (int i = 0; i < 4; ++i) p[1][i] = fexp2(fmaf(a4[i], sc, -24.f));
            }

            if (gk + 31 > q0) {                      // diagonal subtile: mask
#pragma unroll
                for (int nt = 0; nt < 2; ++nt)
#pragma unroll
                    for (int i = 0; i < 4; ++i)
                        if (gk + nt * 16 + col > q0 + quad * 4 + i)
                            p[nt][i] = 0.f;
            }

#pragma unroll
            for (int i = 0; i < 4; ++i) lp[i] += p[0][i] + p[1][i];

            // P: C-layout -> LDS -> A-layout (wave-private, in-order DS)
#pragma unroll
            for (int nt = 0; nt < 2; ++nt)
#pragma unroll
                for (int i = 0; i < 4; ++i)
                    plds[wave][quad * 4 + i][nt * 16 + col] = (bf16)p[nt][i];
            bf16x8 pa = *(const bf16x8*)&plds[wave][col][quad * 8];

#pragma unroll
            for (int h = 0; h < 4; ++h) {
                bf16x8 vb = *(const bf16x8*)&Vt[buf][h * 16 + col][32 * st + quad * 8];
                o[h] = __builtin_amdgcn_mfma_f32_16x16x32_bf16(pa, vb, o[h], 0, 0, 0);
            }
        }

        // ---- write prefetched chunk into other buffer, barrier, swap ----
        if (more) {
#pragma unroll
            for (int it = 0; it < 2; ++it) {
                const int idx = it * 256 + tid;
                const int kr  = idx >> 3;
                const int off = (idx & 7) * 8;
                *(bf16x8*)&Kt[buf ^ 1][kr][off] = kn[it];
                *(bf16x8*)&Vt[buf ^ 1][kr][off] = vn[it];
            }
            __syncthreads();
            buf ^= 1;
        }
    }

    // ---- epilogue: waves own disjoint rows -> direct partial stores ----
    float lr[4];
#pragma unroll
    for (int i = 0; i < 4; ++i) {
        float v = lp[i];
#pragma unroll
        for (int off = 1; off < 16; off <<= 1)
            v += __shfl_xor(v, off, 64);
        lr[i] = v;
    }

    const size_t rowbase = (size_t)b * T_SEQ + q0 + quad * 4;
    if (col == 0) {
#pragma unroll
        for (int i = 0; i < 4; ++i)
            l_parts[(size_t)jc * 16384 + rowbase + i] = lr[i];
    }

    float* dst = (jc == 0) ? out : (o_parts + (size_t)(jc - 1) * 16384 * HS);
#pragma unroll
    for (int h = 0; h < 4; ++h)
#pragma unroll
        for (int i = 0; i < 4; ++i)
            dst[(rowbase + i) * HS + h * 16 + col] = o[h][i];
}

// ---------------------------------------------------------------------------
// Kernel 3: combine job partials and normalize: out = sum(O_j) / sum(l_j).
// ---------------------------------------------------------------------------
__global__ __launch_bounds__(256) void norm_kernel(
    float* __restrict__ out,            // in/out: slot-0 raw -> final
    const float* __restrict__ o_parts,  // [7][B*T][64]
    const float* __restrict__ l_parts)  // [8][B*T]
{
    const int i   = blockIdx.x * 256 + threadIdx.x;   // 0 .. 1048575
    const int row = i >> 6;
    const int qb  = (row & 4095) >> 6;
    const int nj  = (qb >> 3) + 1;      // jobs for this q-block (1..8)

    float s = out[i];
    float L = l_parts[row];
    for (int j = 1; j < nj; ++j) {
        s += o_parts[(size_t)(j - 1) * 1048576 + i];
        L += l_parts[(size_t)j * 16384 + row];
    }
    out[i] = s / L;
}

extern "C" void kernel_launch(void* const* d_in, const int* in_sizes, int n_in,
                              void* d_out, int out_size, void* d_ws, size_t ws_size,
                              hipStream_t stream) {
    const float* x  = (const float*)d_in[0];
    const float* Wk = (const float*)d_in[1];
    const float* Wv = (const float*)d_in[2];
    float* out = (float*)d_out;

    bf16* ws    = (bf16*)d_ws;
    bf16* wbf   = ws;                                    // 256 KB
    bf16* kmat  = ws + (size_t)128 * 1024;               // 2 MB
    bf16* qvmat = kmat + (size_t)16384 * 64;             // 2 MB
    bf16* qvT   = qvmat + (size_t)16384 * 64;            // 2 MB
    float* o_parts = (float*)(qvT + (size_t)16384 * 64); // 28 MB (slots 1-7)
    float* l_parts = o_parts + (size_t)7 * 16384 * 64;   // 512 KB

    wcast_kernel<<<64, 256, 0, stream>>>(Wk, Wv, wbf);
    proj_kernel<<<1024, 256, 0, stream>>>(x, wbf, kmat, qvmat, qvT);
    attn_kernel<<<1152, 256, 0, stream>>>(kmat, qvmat, qvT, out, o_parts, l_parts);
    norm_kernel<<<4096, 256, 0, stream>>>(out, o_parts, l_parts);
}

// Round 9
// 151.213 us; speedup vs baseline: 1.6271x; 1.0918x over previous
//
#include <hip/hip_runtime.h>
#include <hip/hip_bf16.h>

typedef __bf16 bf16;
typedef __attribute__((ext_vector_type(4))) __bf16 bf16x4;
typedef __attribute__((ext_vector_type(8))) __bf16 bf16x8;
typedef __attribute__((ext_vector_type(4))) float f32x4;

#define T_SEQ 4096
#define D_EMB 1024
#define HS 64

__device__ __forceinline__ float fexp2(float x) {
#if __has_builtin(__builtin_amdgcn_exp2f)
    return __builtin_amdgcn_exp2f(x);
#else
    return exp2f(x);
#endif
}

// ---------------------------------------------------------------------------
// Kernel 0: cast Wk|Wv (fp32, 64x1024 each) -> bf16 workspace copies.
// ---------------------------------------------------------------------------
__global__ __launch_bounds__(256) void wcast_kernel(
    const float* __restrict__ Wk, const float* __restrict__ Wv,
    bf16* __restrict__ wbf)   // [128][1024]
{
    const int t = blockIdx.x * 256 + threadIdx.x;
    const int base = t * 8;
    const float* src = (base < 65536) ? (Wk + base) : (Wv + base - 65536);
    float4 f0 = *(const float4*)(src);
    float4 f1 = *(const float4*)(src + 4);
    bf16x8 o = {(__bf16)f0.x, (__bf16)f0.y, (__bf16)f0.z, (__bf16)f0.w,
                (__bf16)f1.x, (__bf16)f1.y, (__bf16)f1.z, (__bf16)f1.w};
    *(bf16x8*)(wbf + base) = o;
}

// ---------------------------------------------------------------------------
// Kernel 1: staged-LDS projection GEMM (round-9 rebuild).
// Block = 64 rows x 128 cols (all N), BK=64, 16 chunks, double-buffered LDS.
// Per chunk: stage x (64x64 fp32 -> bf16, flat coalesced) and W (128x64 bf16,
// 128-B row segments) into padded LDS; MFMA fragments via ds_read_b128 only.
// Wave computes 64 rows x 32 cols (mt 0..3, nt 0..1). Grid 256 = 1 block/CU.
// ---------------------------------------------------------------------------
__global__ __launch_bounds__(256, 2) void proj_kernel(
    const float* __restrict__ x,    // [16384][1024] fp32
    const bf16* __restrict__ wbf,   // [128][1024] bf16 (Wk rows 0-63, Wv 64-127)
    bf16* __restrict__ kmat,        // [16384][64]
    bf16* __restrict__ qvmat,       // [16384][64]
    bf16* __restrict__ qvT)         // [4][64][4096]
{
    __shared__ bf16 xs[2][64][72];    // 18.4 KB total (rows padded to 144 B)
    __shared__ bf16 ws[2][128][72];   // 36.9 KB total

    const int tid  = threadIdx.x;
    const int lane = tid & 63;
    const int wave = tid >> 6;
    const int col  = lane & 15;
    const int quad = lane >> 4;
    const int rowbase = blockIdx.x * 64;

    f32x4 acc[4][2];
#pragma unroll
    for (int mt = 0; mt < 4; ++mt)
#pragma unroll
        for (int nt = 0; nt < 2; ++nt) acc[mt][nt] = {0.f, 0.f, 0.f, 0.f};

    // ---- stage chunk 0 into buffer 0 ----
    {
#pragma unroll
        for (int p = 0; p < 4; ++p) {
            const int idx = p * 256 + tid;          // x: 1024 float4s
            const int xr  = idx >> 4;
            const int c4  = (idx & 15) * 4;
            float4 f = *(const float4*)(x + (size_t)(rowbase + xr) * D_EMB + c4);
            bf16x4 v = {(__bf16)f.x, (__bf16)f.y, (__bf16)f.z, (__bf16)f.w};
            *(bf16x4*)&xs[0][xr][c4] = v;
        }
#pragma unroll
        for (int p = 0; p < 4; ++p) {
            const int idx = p * 256 + tid;          // W: 1024 bf16x8s
            const int wr  = idx >> 3;
            const int off = (idx & 7) * 8;
            *(bf16x8*)&ws[0][wr][off] = *(const bf16x8*)(wbf + (size_t)wr * D_EMB + off);
        }
    }
    __syncthreads();

    int buf = 0;
#pragma unroll 1
    for (int c = 0; c < 16; ++c) {
        const bool more = (c + 1 < 16);

        // ---- prefetch next chunk into registers (coalesced) ----
        float4 xn[4];
        bf16x8 wn[4];
        if (more) {
            const int k0 = (c + 1) * 64;
#pragma unroll
            for (int p = 0; p < 4; ++p) {
                const int idx = p * 256 + tid;
                const int xr  = idx >> 4;
                const int c4  = (idx & 15) * 4;
                xn[p] = *(const float4*)(x + (size_t)(rowbase + xr) * D_EMB + k0 + c4);
            }
#pragma unroll
            for (int p = 0; p < 4; ++p) {
                const int idx = p * 256 + tid;
                const int wr  = idx >> 3;
                const int off = (idx & 7) * 8;
                wn[p] = *(const bf16x8*)(wbf + (size_t)wr * D_EMB + k0 + off);
            }
        }

        // ---- compute chunk c from LDS ----
#pragma unroll
        for (int s = 0; s < 2; ++s) {
            bf16x8 af[4];
#pragma unroll
            for (int mt = 0; mt < 4; ++mt)
                af[mt] = *(const bf16x8*)&xs[buf][mt * 16 + col][s * 32 + quad * 8];
            bf16x8 bfr[2];
#pragma unroll
            for (int nt = 0; nt < 2; ++nt)
                bfr[nt] = *(const bf16x8*)&ws[buf][wave * 32 + nt * 16 + col][s * 32 + quad * 8];
#pragma unroll
            for (int mt = 0; mt < 4; ++mt)
#pragma unroll
                for (int nt = 0; nt < 2; ++nt)
                    acc[mt][nt] = __builtin_amdgcn_mfma_f32_16x16x32_bf16(
                        af[mt], bfr[nt], acc[mt][nt], 0, 0, 0);
        }

        // ---- write prefetched chunk, barrier, swap ----
        if (more) {
#pragma unroll
            for (int p = 0; p < 4; ++p) {
                const int idx = p * 256 + tid;
                const int xr  = idx >> 4;
                const int c4  = (idx & 15) * 4;
                bf16x4 v = {(__bf16)xn[p].x, (__bf16)xn[p].y,
                            (__bf16)xn[p].z, (__bf16)xn[p].w};
                *(bf16x4*)&xs[buf ^ 1][xr][c4] = v;
            }
#pragma unroll
            for (int p = 0; p < 4; ++p) {
                const int idx = p * 256 + tid;
                const int wr  = idx >> 3;
                const int off = (idx & 7) * 8;
                *(bf16x8*)&ws[buf ^ 1][wr][off] = wn[p];
            }
            __syncthreads();
            buf ^= 1;
        }
    }

    // ---- epilogue: C layout col=lane&15, row=quad*4+reg ----
    // wave owns n-cols [wave*32, wave*32+32): waves 0,1 -> kmat; 2,3 -> qvmat.
#pragma unroll
    for (int mt = 0; mt < 4; ++mt)
#pragma unroll
        for (int nt = 0; nt < 2; ++nt) {
            const int gcol = wave * 32 + nt * 16 + col;
#pragma unroll
            for (int r = 0; r < 4; ++r) {
                const int grow = rowbase + mt * 16 + quad * 4 + r;
                bf16 bv = (bf16)acc[mt][nt][r];
                if (gcol < 64) {
                    kmat[(size_t)grow * HS + gcol] = bv;
                } else {
                    const int h = gcol - 64;
                    qvmat[(size_t)grow * HS + h] = bv;
                    const int bb = grow >> 12;
                    const int tt = grow & (T_SEQ - 1);
                    qvT[((size_t)bb * HS + h) * T_SEQ + tt] = bv;
                }
            }
        }
}

// ---------------------------------------------------------------------------
// Kernel 2: staged-LDS causal attention (unchanged from round 8).
// ---------------------------------------------------------------------------
__global__ __launch_bounds__(256, 3) void attn_kernel(
    const bf16* __restrict__ kmat,   // [B*T][64]
    const bf16* __restrict__ qvmat,  // [B*T][64]
    const bf16* __restrict__ qvT,    // [B][64][T]
    float* __restrict__ out,         // [B*T][64] raw O partial, slot 0
    float* __restrict__ o_parts,     // [7][B*T][64] raw O partials, slots 1-7
    float* __restrict__ l_parts)     // [8][B*T] l partials
{
    __shared__ bf16 Kt[2][64][72];
    __shared__ bf16 Vt[2][64][72];
    __shared__ bf16 plds[4][16][40];

    const int tid  = threadIdx.x;
    const int lane = tid & 63;
    const int wave = tid >> 6;
    const int col  = lane & 15;
    const int quad = lane >> 4;

    const int b = blockIdx.x / 288;
    const int r = blockIdx.x - b * 288;
    int a = 0;
    while (4 * (a + 1) * (a + 2) <= r) ++a;
    const int rr = r - 4 * a * (a + 1);
    const int m  = rr / (a + 1);
    const int jc = rr - m * (a + 1);
    const int qb = 8 * a + m;

    const int cbeg  = jc * 8;
    const int nctot = qb + 1;
    const int cend  = (nctot < cbeg + 8) ? nctot : cbeg + 8;

    const bf16* qvb = qvmat + (size_t)b * T_SEQ * HS;
    const bf16* kb  = kmat  + (size_t)b * T_SEQ * HS;
    const bf16* vTb = qvT   + (size_t)b * HS * T_SEQ;

    const int q0 = qb * 64 + wave * 16;

    bf16x8 qf0 = *(const bf16x8*)(qvb + (size_t)(q0 + col) * HS + quad * 8);
    bf16x8 qf1 = *(const bf16x8*)(qvb + (size_t)(q0 + col) * HS + 32 + quad * 8);

    f32x4 o[4];
    float lp[4];
#pragma unroll
    for (int h = 0; h < 4; ++h) o[h] = {0.f, 0.f, 0.f, 0.f};
#pragma unroll
    for (int i = 0; i < 4; ++i) lp[i] = 0.f;

    const float sc = 0.125f * 1.44269504088896f;

    {
        const int kc = cbeg * 64;
#pragma unroll
        for (int it = 0; it < 2; ++it) {
            const int idx = it * 256 + tid;
            const int kr  = idx >> 3;
            const int off = (idx & 7) * 8;
            bf16x8 kv = *(const bf16x8*)(kb + (size_t)kc * HS + idx * 8);
            bf16x8 vv = *(const bf16x8*)(vTb + (size_t)kr * T_SEQ + kc + off);
            *(bf16x8*)&Kt[0][kr][off] = kv;
            *(bf16x8*)&Vt[0][kr][off] = vv;
        }
    }
    __syncthreads();

    int buf = 0;
#pragma unroll 1
    for (int c = cbeg; c < cend; ++c) {
        const bool more = (c + 1 < cend);

        bf16x8 kn[2], vn[2];
        if (more) {
            const int kcn = (c + 1) * 64;
#pragma unroll
            for (int it = 0; it < 2; ++it) {
                const int idx = it * 256 + tid;
                const int kr  = idx >> 3;
                const int off = (idx & 7) * 8;
                kn[it] = *(const bf16x8*)(kb + (size_t)kcn * HS + idx * 8);
                vn[it] = *(const bf16x8*)(vTb + (size_t)kr * T_SEQ + kcn + off);
            }
        }

        const int kc = c * 64;
#pragma unroll
        for (int st = 0; st < 2; ++st) {
            const int gk = kc + 32 * st;
            if (gk > q0 + 15) break;

            bf16x8 b0 = *(const bf16x8*)&Kt[buf][32 * st + col][quad * 8];
            bf16x8 b1 = *(const bf16x8*)&Kt[buf][32 * st + col][32 + quad * 8];
            bf16x8 b2 = *(const bf16x8*)&Kt[buf][32 * st + 16 + col][quad * 8];
            bf16x8 b3 = *(const bf16x8*)&Kt[buf][32 * st + 16 + col][32 + quad * 8];

            float p[2][4];
            {
                f32x4 a4 = {0.f, 0.f, 0.f, 0.f};
                a4 = __builtin_amdgcn_mfma_f32_16x16x32_bf16(qf0, b0, a4, 0, 0, 0);
                a4 = __builtin_amdgcn_mfma_f32_16x16x32_bf16(qf1, b1, a4, 0, 0, 0);
#pragma unroll
                for (int i = 0; i < 4; ++i) p[0][i] = fexp2(fmaf(a4[i], sc, -24.f));
            }
            {
                f32x4 a4 = {0.f, 0.f, 0.f, 0.f};
                a4 = __builtin_amdgcn_mfma_f32_16x16x32_bf16(qf0, b2, a4, 0, 0, 0);
                a4 = __builtin_amdgcn_mfma_f32_16x16x32_bf16(qf1, b3, a4, 0, 0, 0);
#pragma unroll
                for (int i = 0; i < 4; ++i) p[1][i] = fexp2(fmaf(a4[i], sc, -24.f));
            }

            if (gk + 31 > q0) {
#pragma unroll
                for (int nt = 0; nt < 2; ++nt)
#pragma unroll
                    for (int i = 0; i < 4; ++i)
                        if (gk + nt * 16 + col > q0 + quad * 4 + i)
                            p[nt][i] = 0.f;
            }

#pragma unroll
            for (int i = 0; i < 4; ++i) lp[i] += p[0][i] + p[1][i];

#pragma unroll
            for (int nt = 0; nt < 2; ++nt)
#pragma unroll
                for (int i = 0; i < 4; ++i)
                    plds[wave][quad * 4 + i][nt * 16 + col] = (bf16)p[nt][i];
            bf16x8 pa = *(const bf16x8*)&plds[wave][col][quad * 8];

#pragma unroll
            for (int h = 0; h < 4; ++h) {
                bf16x8 vb = *(const bf16x8*)&Vt[buf][h * 16 + col][32 * st + quad * 8];
                o[h] = __builtin_amdgcn_mfma_f32_16x16x32_bf16(pa, vb, o[h], 0, 0, 0);
            }
        }

        if (more) {
#pragma unroll
            for (int it = 0; it < 2; ++it) {
                const int idx = it * 256 + tid;
                const int kr  = idx >> 3;
                const int off = (idx & 7) * 8;
                *(bf16x8*)&Kt[buf ^ 1][kr][off] = kn[it];
                *(bf16x8*)&Vt[buf ^ 1][kr][off] = vn[it];
            }
            __syncthreads();
            buf ^= 1;
        }
    }

    float lr[4];
#pragma unroll
    for (int i = 0; i < 4; ++i) {
        float v = lp[i];
#pragma unroll
        for (int off = 1; off < 16; off <<= 1)
            v += __shfl_xor(v, off, 64);
        lr[i] = v;
    }

    const size_t rowbase = (size_t)b * T_SEQ + q0 + quad * 4;
    if (col == 0) {
#pragma unroll
        for (int i = 0; i < 4; ++i)
            l_parts[(size_t)jc * 16384 + rowbase + i] = lr[i];
    }

    float* dst = (jc == 0) ? out : (o_parts + (size_t)(jc - 1) * 16384 * HS);
#pragma unroll
    for (int h = 0; h < 4; ++h)
#pragma unroll
        for (int i = 0; i < 4; ++i)
            dst[(rowbase + i) * HS + h * 16 + col] = o[h][i];
}

// ---------------------------------------------------------------------------
// Kernel 3: combine job partials and normalize: out = sum(O_j) / sum(l_j).
// ---------------------------------------------------------------------------
__global__ __launch_bounds__(256) void norm_kernel(
    float* __restrict__ out,
    const float* __restrict__ o_parts,  // [7][B*T][64]
    const float* __restrict__ l_parts)  // [8][B*T]
{
    const int i   = blockIdx.x * 256 + threadIdx.x;
    const int row = i >> 6;
    const int qb  = (row & 4095) >> 6;
    const int nj  = (qb >> 3) + 1;

    float s = out[i];
    float L = l_parts[row];
    for (int j = 1; j < nj; ++j) {
        s += o_parts[(size_t)(j - 1) * 1048576 + i];
        L += l_parts[(size_t)j * 16384 + row];
    }
    out[i] = s / L;
}

extern "C" void kernel_launch(void* const* d_in, const int* in_sizes, int n_in,
                              void* d_out, int out_size, void* d_ws, size_t ws_size,
                              hipStream_t stream) {
    const float* x  = (const float*)d_in[0];
    const float* Wk = (const float*)d_in[1];
    const float* Wv = (const float*)d_in[2];
    float* out = (float*)d_out;

    bf16* ws    = (bf16*)d_ws;
    bf16* wbf   = ws;                                    // 256 KB
    bf16* kmat  = ws + (size_t)128 * 1024;               // 2 MB
    bf16* qvmat = kmat + (size_t)16384 * 64;             // 2 MB
    bf16* qvT   = qvmat + (size_t)16384 * 64;            // 2 MB
    float* o_parts = (float*)(qvT + (size_t)16384 * 64); // 28 MB (slots 1-7)
    float* l_parts = o_parts + (size_t)7 * 16384 * 64;   // 512 KB

    wcast_kernel<<<64, 256, 0, stream>>>(Wk, Wv, wbf);
    proj_kernel<<<256, 256, 0, stream>>>(x, wbf, kmat, qvmat, qvT);
    attn_kernel<<<1152, 256, 0, stream>>>(kmat, qvmat, qvT, out, o_parts, l_parts);
    norm_kernel<<<4096, 256, 0, stream>>>(out, o_parts, l_parts);
}

// Round 10
// 147.193 us; speedup vs baseline: 1.6715x; 1.0273x over previous
//
#include <hip/hip_runtime.h>
#include <hip/hip_bf16.h>

typedef __bf16 bf16;
typedef __attribute__((ext_vector_type(4))) __bf16 bf16x4;
typedef __attribute__((ext_vector_type(8))) __bf16 bf16x8;
typedef __attribute__((ext_vector_type(4))) float f32x4;

#define T_SEQ 4096
#define D_EMB 1024
#define HS 64

__device__ __forceinline__ float fexp2(float x) {
#if __has_builtin(__builtin_amdgcn_exp2f)
    return __builtin_amdgcn_exp2f(x);
#else
    return exp2f(x);
#endif
}

// ---------------------------------------------------------------------------
// Kernel 0: cast Wk|Wv (fp32, 64x1024 each) -> bf16 workspace copies.
// ---------------------------------------------------------------------------
__global__ __launch_bounds__(256) void wcast_kernel(
    const float* __restrict__ Wk, const float* __restrict__ Wv,
    bf16* __restrict__ wbf)   // [128][1024]
{
    const int t = blockIdx.x * 256 + threadIdx.x;
    const int base = t * 8;
    const float* src = (base < 65536) ? (Wk + base) : (Wv + base - 65536);
    float4 f0 = *(const float4*)(src);
    float4 f1 = *(const float4*)(src + 4);
    bf16x8 o = {(__bf16)f0.x, (__bf16)f0.y, (__bf16)f0.z, (__bf16)f0.w,
                (__bf16)f1.x, (__bf16)f1.y, (__bf16)f1.z, (__bf16)f1.w};
    *(bf16x8*)(wbf + base) = o;
}

// ---------------------------------------------------------------------------
// Kernel 1: staged-LDS projection GEMM, BM=32, split-K x2.
// Grid 1024 = 512 row-blocks x 2 K-halves -> 4 blocks/CU (LDS 23 KB, 2-barrier
// single-buffer loop + register prefetch; cross-block TLP hides staging).
// Writes fp32 partials pbuf[2][16384][128]; pcomb_kernel combines.
// ---------------------------------------------------------------------------
__global__ __launch_bounds__(256, 4) void proj_kernel(
    const float* __restrict__ x,    // [16384][1024] fp32
    const bf16* __restrict__ wbf,   // [128][1024] bf16 (Wk rows 0-63, Wv 64-127)
    float* __restrict__ pbuf)       // [2][16384][128] fp32 partials
{
    __shared__ bf16 xs[32][72];     // 4.6 KB
    __shared__ bf16 wsh[128][72];   // 18.4 KB

    const int tid  = threadIdx.x;
    const int lane = tid & 63;
    const int wave = tid >> 6;
    const int col  = lane & 15;
    const int quad = lane >> 4;

    const int mb = blockIdx.x & 511;
    const int kh = blockIdx.x >> 9;          // K half 0/1
    const int rowbase = mb * 32;
    const int kbase   = kh * 512;

    f32x4 acc[2][2];
#pragma unroll
    for (int mt = 0; mt < 2; ++mt)
#pragma unroll
        for (int nt = 0; nt < 2; ++nt) acc[mt][nt] = {0.f, 0.f, 0.f, 0.f};

    // register prefetch of chunk 0
    float4 xn[2];
    bf16x8 wn[4];
    {
#pragma unroll
        for (int p = 0; p < 2; ++p) {
            const int idx = p * 256 + tid;          // 512 float4s: x 32x64
            const int xr  = idx >> 4;
            const int c4  = (idx & 15) * 4;
            xn[p] = *(const float4*)(x + (size_t)(rowbase + xr) * D_EMB + kbase + c4);
        }
#pragma unroll
        for (int p = 0; p < 4; ++p) {
            const int idx = p * 256 + tid;          // 1024 bf16x8s: W 128x64
            const int wr  = idx >> 3;
            const int off = (idx & 7) * 8;
            wn[p] = *(const bf16x8*)(wbf + (size_t)wr * D_EMB + kbase + off);
        }
    }

#pragma unroll 1
    for (int c = 0; c < 8; ++c) {
        // ---- write prefetched chunk into LDS ----
#pragma unroll
        for (int p = 0; p < 2; ++p) {
            const int idx = p * 256 + tid;
            const int xr  = idx >> 4;
            const int c4  = (idx & 15) * 4;
            bf16x4 v = {(__bf16)xn[p].x, (__bf16)xn[p].y,
                        (__bf16)xn[p].z, (__bf16)xn[p].w};
            *(bf16x4*)&xs[xr][c4] = v;
        }
#pragma unroll
        for (int p = 0; p < 4; ++p) {
            const int idx = p * 256 + tid;
            const int wr  = idx >> 3;
            const int off = (idx & 7) * 8;
            *(bf16x8*)&wsh[wr][off] = wn[p];
        }
        __syncthreads();

        // ---- issue next chunk's loads (hidden behind compute) ----
        if (c < 7) {
            const int k0 = kbase + (c + 1) * 64;
#pragma unroll
            for (int p = 0; p < 2; ++p) {
                const int idx = p * 256 + tid;
                const int xr  = idx >> 4;
                const int c4  = (idx & 15) * 4;
                xn[p] = *(const float4*)(x + (size_t)(rowbase + xr) * D_EMB + k0 + c4);
            }
#pragma unroll
            for (int p = 0; p < 4; ++p) {
                const int idx = p * 256 + tid;
                const int wr  = idx >> 3;
                const int off = (idx & 7) * 8;
                wn[p] = *(const bf16x8*)(wbf + (size_t)wr * D_EMB + k0 + off);
            }
        }

        // ---- compute chunk from LDS ----
#pragma unroll
        for (int s = 0; s < 2; ++s) {
            bf16x8 af[2];
#pragma unroll
            for (int mt = 0; mt < 2; ++mt)
                af[mt] = *(const bf16x8*)&xs[mt * 16 + col][s * 32 + quad * 8];
            bf16x8 bfr[2];
#pragma unroll
            for (int nt = 0; nt < 2; ++nt)
                bfr[nt] = *(const bf16x8*)&wsh[wave * 32 + nt * 16 + col][s * 32 + quad * 8];
#pragma unroll
            for (int mt = 0; mt < 2; ++mt)
#pragma unroll
                for (int nt = 0; nt < 2; ++nt)
                    acc[mt][nt] = __builtin_amdgcn_mfma_f32_16x16x32_bf16(
                        af[mt], bfr[nt], acc[mt][nt], 0, 0, 0);
        }
        __syncthreads();
    }

    // ---- store fp32 partials: C layout col=lane&15, row=quad*4+reg ----
    float* ph = pbuf + (size_t)kh * 16384 * 128;
#pragma unroll
    for (int mt = 0; mt < 2; ++mt)
#pragma unroll
        for (int nt = 0; nt < 2; ++nt) {
            const int gcol = wave * 32 + nt * 16 + col;
#pragma unroll
            for (int r = 0; r < 4; ++r) {
                const int grow = rowbase + mt * 16 + quad * 4 + r;
                ph[(size_t)grow * 128 + gcol] = acc[mt][nt][r];
            }
        }
}

// ---------------------------------------------------------------------------
// Kernel 1b: combine K-halves, cast to bf16, write kmat/qvmat/qvT.
// 262144 threads: thread = (row, 8-col group).
// ---------------------------------------------------------------------------
__global__ __launch_bounds__(256) void pcomb_kernel(
    const float* __restrict__ pbuf,  // [2][16384][128]
    bf16* __restrict__ kmat,         // [16384][64]
    bf16* __restrict__ qvmat,        // [16384][64]
    bf16* __restrict__ qvT)          // [4][64][4096]
{
    const int g   = blockIdx.x * 256 + threadIdx.x;
    const int row = g >> 4;
    const int cg  = g & 15;
    const size_t base = (size_t)row * 128 + cg * 8;

    f32x4 a0 = *(const f32x4*)(pbuf + base);
    f32x4 a1 = *(const f32x4*)(pbuf + base + 4);
    f32x4 b0 = *(const f32x4*)(pbuf + (size_t)16384 * 128 + base);
    f32x4 b1 = *(const f32x4*)(pbuf + (size_t)16384 * 128 + base + 4);
    a0 += b0; a1 += b1;
    bf16x8 v = {(__bf16)a0[0], (__bf16)a0[1], (__bf16)a0[2], (__bf16)a0[3],
                (__bf16)a1[0], (__bf16)a1[1], (__bf16)a1[2], (__bf16)a1[3]};

    if (cg < 8) {
        *(bf16x8*)(kmat + (size_t)row * HS + cg * 8) = v;
    } else {
        const int h0 = (cg - 8) * 8;
        *(bf16x8*)(qvmat + (size_t)row * HS + h0) = v;
        const int bb = row >> 12;
        const int tt = row & (T_SEQ - 1);
#pragma unroll
        for (int j = 0; j < 8; ++j)
            qvT[((size_t)bb * HS + h0 + j) * T_SEQ + tt] = v[j];
    }
}

// ---------------------------------------------------------------------------
// Kernel 2: staged-LDS causal attention, fixed-offset softmax, q = v.
// Single-buffered LDS (23.4 KB) + register prefetch across the chunk barrier
// -> 5 blocks/CU (launch_bounds(256,5)), 5 waves/SIMD. Heavy jobs dispatch
// first (reversed job index). Partial (O, l) per job slot; norm combines.
// ---------------------------------------------------------------------------
__global__ __launch_bounds__(256, 5) void attn_kernel(
    const bf16* __restrict__ kmat,   // [B*T][64]
    const bf16* __restrict__ qvmat,  // [B*T][64]
    const bf16* __restrict__ qvT,    // [B][64][T]
    float* __restrict__ out,         // [B*T][64] raw O partial, slot 0
    float* __restrict__ o_parts,     // [7][B*T][64] raw O partials, slots 1-7
    float* __restrict__ l_parts)     // [8][B*T] l partials
{
    __shared__ bf16 Kt[64][72];      // 9.2 KB
    __shared__ bf16 Vt[64][72];      // 9.2 KB
    __shared__ bf16 plds[4][16][40]; // 5 KB

    const int tid  = threadIdx.x;
    const int lane = tid & 63;
    const int wave = tid >> 6;
    const int col  = lane & 15;
    const int quad = lane >> 4;

    const int b = blockIdx.x / 288;
    const int r = 287 - (blockIdx.x - b * 288);   // heavy tiers first
    int a = 0;
    while (4 * (a + 1) * (a + 2) <= r) ++a;       // a in 0..7
    const int rr = r - 4 * a * (a + 1);
    const int m  = rr / (a + 1);
    const int jc = rr - m * (a + 1);              // job slot 0..a
    const int qb = 8 * a + m;                     // q-block 0..63

    const int cbeg  = jc * 8;
    const int nctot = qb + 1;
    const int cend  = (nctot < cbeg + 8) ? nctot : cbeg + 8;

    const bf16* qvb = qvmat + (size_t)b * T_SEQ * HS;
    const bf16* kb  = kmat  + (size_t)b * T_SEQ * HS;
    const bf16* vTb = qvT   + (size_t)b * HS * T_SEQ;

    const int q0 = qb * 64 + wave * 16;

    bf16x8 qf0 = *(const bf16x8*)(qvb + (size_t)(q0 + col) * HS + quad * 8);
    bf16x8 qf1 = *(const bf16x8*)(qvb + (size_t)(q0 + col) * HS + 32 + quad * 8);

    f32x4 o[4];
    float lp[4];
#pragma unroll
    for (int h = 0; h < 4; ++h) o[h] = {0.f, 0.f, 0.f, 0.f};
#pragma unroll
    for (int i = 0; i < 4; ++i) lp[i] = 0.f;

    const float sc = 0.125f * 1.44269504088896f;

    // register prefetch of first chunk
    bf16x8 kn[2], vn[2];
    {
        const int kc = cbeg * 64;
#pragma unroll
        for (int it = 0; it < 2; ++it) {
            const int idx = it * 256 + tid;
            const int kr  = idx >> 3;
            const int off = (idx & 7) * 8;
            kn[it] = *(const bf16x8*)(kb + (size_t)kc * HS + idx * 8);
            vn[it] = *(const bf16x8*)(vTb + (size_t)kr * T_SEQ + kc + off);
        }
    }

#pragma unroll 1
    for (int c = cbeg; c < cend; ++c) {
        // ---- write prefetched chunk into LDS ----
#pragma unroll
        for (int it = 0; it < 2; ++it) {
            const int idx = it * 256 + tid;
            const int kr  = idx >> 3;
            const int off = (idx & 7) * 8;
            *(bf16x8*)&Kt[kr][off] = kn[it];
            *(bf16x8*)&Vt[kr][off] = vn[it];
        }
        __syncthreads();

        // ---- issue next chunk's loads (hidden behind compute) ----
        if (c + 1 < cend) {
            const int kcn = (c + 1) * 64;
#pragma unroll
            for (int it = 0; it < 2; ++it) {
                const int idx = it * 256 + tid;
                const int kr  = idx >> 3;
                const int off = (idx & 7) * 8;
                kn[it] = *(const bf16x8*)(kb + (size_t)kcn * HS + idx * 8);
                vn[it] = *(const bf16x8*)(vTb + (size_t)kr * T_SEQ + kcn + off);
            }
        }

        // ---- compute chunk c from LDS ----
        const int kc = c * 64;
#pragma unroll
        for (int st = 0; st < 2; ++st) {
            const int gk = kc + 32 * st;
            if (gk > q0 + 15) break;             // fully masked (wave-uniform)

            bf16x8 b0 = *(const bf16x8*)&Kt[32 * st + col][quad * 8];
            bf16x8 b1 = *(const bf16x8*)&Kt[32 * st + col][32 + quad * 8];
            bf16x8 b2 = *(const bf16x8*)&Kt[32 * st + 16 + col][quad * 8];
            bf16x8 b3 = *(const bf16x8*)&Kt[32 * st + 16 + col][32 + quad * 8];

            float p[2][4];
            {
                f32x4 a4 = {0.f, 0.f, 0.f, 0.f};
                a4 = __builtin_amdgcn_mfma_f32_16x16x32_bf16(qf0, b0, a4, 0, 0, 0);
                a4 = __builtin_amdgcn_mfma_f32_16x16x32_bf16(qf1, b1, a4, 0, 0, 0);
#pragma unroll
                for (int i = 0; i < 4; ++i) p[0][i] = fexp2(fmaf(a4[i], sc, -24.f));
            }
            {
                f32x4 a4 = {0.f, 0.f, 0.f, 0.f};
                a4 = __builtin_amdgcn_mfma_f32_16x16x32_bf16(qf0, b2, a4, 0, 0, 0);
                a4 = __builtin_amdgcn_mfma_f32_16x16x32_bf16(qf1, b3, a4, 0, 0, 0);
#pragma unroll
                for (int i = 0; i < 4; ++i) p[1][i] = fexp2(fmaf(a4[i], sc, -24.f));
            }

            if (gk + 31 > q0) {                  // diagonal subtile: mask
#pragma unroll
                for (int nt = 0; nt < 2; ++nt)
#pragma unroll
                    for (int i = 0; i < 4; ++i)
                        if (gk + nt * 16 + col > q0 + quad * 4 + i)
                            p[nt][i] = 0.f;
            }

#pragma unroll
            for (int i = 0; i < 4; ++i) lp[i] += p[0][i] + p[1][i];

            // P: C-layout -> LDS -> A-layout (wave-private, in-order DS)
#pragma unroll
            for (int nt = 0; nt < 2; ++nt)
#pragma unroll
                for (int i = 0; i < 4; ++i)
                    plds[wave][quad * 4 + i][nt * 16 + col] = (bf16)p[nt][i];
            bf16x8 pa = *(const bf16x8*)&plds[wave][col][quad * 8];

#pragma unroll
            for (int h = 0; h < 4; ++h) {
                bf16x8 vb = *(const bf16x8*)&Vt[h * 16 + col][32 * st + quad * 8];
                o[h] = __builtin_amdgcn_mfma_f32_16x16x32_bf16(pa, vb, o[h], 0, 0, 0);
            }
        }
        __syncthreads();   // protect Kt/Vt before next write
    }

    // ---- epilogue: waves own disjoint rows -> direct partial stores ----
    float lr[4];
#pragma unroll
    for (int i = 0; i < 4; ++i) {
        float v = lp[i];
#pragma unroll
        for (int off = 1; off < 16; off <<= 1)
            v += __shfl_xor(v, off, 64);
        lr[i] = v;
    }

    const size_t rowbase = (size_t)b * T_SEQ + q0 + quad * 4;
    if (col == 0) {
#pragma unroll
        for (int i = 0; i < 4; ++i)
            l_parts[(size_t)jc * 16384 + rowbase + i] = lr[i];
    }

    float* dst = (jc == 0) ? out : (o_parts + (size_t)(jc - 1) * 16384 * HS);
#pragma unroll
    for (int h = 0; h < 4; ++h)
#pragma unroll
        for (int i = 0; i < 4; ++i)
            dst[(rowbase + i) * HS + h * 16 + col] = o[h][i];
}

// ---------------------------------------------------------------------------
// Kernel 3: combine job partials and normalize: out = sum(O_j) / sum(l_j).
// ---------------------------------------------------------------------------
__global__ __launch_bounds__(256) void norm_kernel(
    float* __restrict__ out,
    const float* __restrict__ o_parts,  // [7][B*T][64]
    const float* __restrict__ l_parts)  // [8][B*T]
{
    const int i   = blockIdx.x * 256 + threadIdx.x;
    const int row = i >> 6;
    const int qb  = (row & 4095) >> 6;
    const int nj  = (qb >> 3) + 1;

    float s = out[i];
    float L = l_parts[row];
    for (int j = 1; j < nj; ++j) {
        s += o_parts[(size_t)(j - 1) * 1048576 + i];
        L += l_parts[(size_t)j * 16384 + row];
    }
    out[i] = s / L;
}

extern "C" void kernel_launch(void* const* d_in, const int* in_sizes, int n_in,
                              void* d_out, int out_size, void* d_ws, size_t ws_size,
                              hipStream_t stream) {
    const float* x  = (const float*)d_in[0];
    const float* Wk = (const float*)d_in[1];
    const float* Wv = (const float*)d_in[2];
    float* out = (float*)d_out;

    bf16* ws    = (bf16*)d_ws;
    bf16* wbf   = ws;                                    // 256 KB
    bf16* kmat  = ws + (size_t)128 * 1024;               // 2 MB
    bf16* qvmat = kmat + (size_t)16384 * 64;             // 2 MB
    bf16* qvT   = qvmat + (size_t)16384 * 64;            // 2 MB
    float* o_parts = (float*)(qvT + (size_t)16384 * 64); // 28 MB (slots 1-7)
    float* l_parts = o_parts + (size_t)7 * 16384 * 64;   // 512 KB
    float* pbuf    = l_parts + (size_t)8 * 16384;        // 16 MB fp32 partials

    wcast_kernel<<<64, 256, 0, stream>>>(Wk, Wv, wbf);
    proj_kernel<<<1024, 256, 0, stream>>>(x, wbf, pbuf);
    pcomb_kernel<<<1024, 256, 0, stream>>>(pbuf, kmat, qvmat, qvT);
    attn_kernel<<<1152, 256, 0, stream>>>(kmat, qvmat, qvT, out, o_parts, l_parts);
    norm_kernel<<<4096, 256, 0, stream>>>(out, o_parts, l_parts);
}

// Round 11
// 137.615 us; speedup vs baseline: 1.7879x; 1.0696x over previous
//
#include <hip/hip_runtime.h>
#include <hip/hip_bf16.h>

typedef __bf16 bf16;
typedef __attribute__((ext_vector_type(4))) __bf16 bf16x4;
typedef __attribute__((ext_vector_type(8))) __bf16 bf16x8;
typedef __attribute__((ext_vector_type(4))) float f32x4;

#define T_SEQ 4096
#define D_EMB 1024
#define HS 64

__device__ __forceinline__ float fexp2(float x) {
#if __has_builtin(__builtin_amdgcn_exp2f)
    return __builtin_amdgcn_exp2f(x);
#else
    return exp2f(x);
#endif
}

// ---------------------------------------------------------------------------
// Kernel 0: cast Wk|Wv (fp32, 64x1024 each) -> bf16 workspace copies.
// ---------------------------------------------------------------------------
__global__ __launch_bounds__(256) void wcast_kernel(
    const float* __restrict__ Wk, const float* __restrict__ Wv,
    bf16* __restrict__ wbf)   // [128][1024]
{
    const int t = blockIdx.x * 256 + threadIdx.x;
    const int base = t * 8;
    const float* src = (base < 65536) ? (Wk + base) : (Wv + base - 65536);
    float4 f0 = *(const float4*)(src);
    float4 f1 = *(const float4*)(src + 4);
    bf16x8 o = {(__bf16)f0.x, (__bf16)f0.y, (__bf16)f0.z, (__bf16)f0.w,
                (__bf16)f1.x, (__bf16)f1.y, (__bf16)f1.z, (__bf16)f1.w};
    *(bf16x8*)(wbf + base) = o;
}

// ---------------------------------------------------------------------------
// Kernel 1: staged-LDS projection GEMM, BM=32, full N=128, no split-K.
// Grid 512 = 2 blocks/CU. Single-buffer LDS (23 KB) + register prefetch,
// 2-barrier chunk loop; cross-block TLP hides the barrier drains.
// Direct bf16 epilogue; qvT built via in-LDS transpose -> coalesced stores.
// ---------------------------------------------------------------------------
__global__ __launch_bounds__(256, 2) void proj_kernel(
    const float* __restrict__ x,    // [16384][1024] fp32
    const bf16* __restrict__ wbf,   // [128][1024] bf16 (Wk rows 0-63, Wv 64-127)
    bf16* __restrict__ kmat,        // [16384][64]
    bf16* __restrict__ qvmat,       // [16384][64]
    bf16* __restrict__ qvT)         // [4][64][4096]
{
    __shared__ bf16 xs[32][72];     // 4.6 KB  (rows padded to 144 B)
    __shared__ bf16 wsh[128][72];   // 18.4 KB
    __shared__ bf16 vt[64][40];     // 5 KB    (qv transpose tile, 80 B rows)

    const int tid  = threadIdx.x;
    const int lane = tid & 63;
    const int wave = tid >> 6;
    const int col  = lane & 15;
    const int quad = lane >> 4;
    const int rowbase = blockIdx.x * 32;

    f32x4 acc[2][2];
#pragma unroll
    for (int mt = 0; mt < 2; ++mt)
#pragma unroll
        for (int nt = 0; nt < 2; ++nt) acc[mt][nt] = {0.f, 0.f, 0.f, 0.f};

    // register prefetch of chunk 0
    float4 xn[2];
    bf16x8 wn[4];
    {
#pragma unroll
        for (int p = 0; p < 2; ++p) {
            const int idx = p * 256 + tid;          // 512 float4s: x 32x64
            const int xr  = idx >> 4;
            const int c4  = (idx & 15) * 4;
            xn[p] = *(const float4*)(x + (size_t)(rowbase + xr) * D_EMB + c4);
        }
#pragma unroll
        for (int p = 0; p < 4; ++p) {
            const int idx = p * 256 + tid;          // 1024 bf16x8s: W 128x64
            const int wr  = idx >> 3;
            const int off = (idx & 7) * 8;
            wn[p] = *(const bf16x8*)(wbf + (size_t)wr * D_EMB + off);
        }
    }

#pragma unroll 1
    for (int c = 0; c < 16; ++c) {
        // ---- write prefetched chunk into LDS ----
#pragma unroll
        for (int p = 0; p < 2; ++p) {
            const int idx = p * 256 + tid;
            const int xr  = idx >> 4;
            const int c4  = (idx & 15) * 4;
            bf16x4 v = {(__bf16)xn[p].x, (__bf16)xn[p].y,
                        (__bf16)xn[p].z, (__bf16)xn[p].w};
            *(bf16x4*)&xs[xr][c4] = v;
        }
#pragma unroll
        for (int p = 0; p < 4; ++p) {
            const int idx = p * 256 + tid;
            const int wr  = idx >> 3;
            const int off = (idx & 7) * 8;
            *(bf16x8*)&wsh[wr][off] = wn[p];
        }
        __syncthreads();

        // ---- issue next chunk's loads (hidden behind compute) ----
        if (c < 15) {
            const int k0 = (c + 1) * 64;
#pragma unroll
            for (int p = 0; p < 2; ++p) {
                const int idx = p * 256 + tid;
                const int xr  = idx >> 4;
                const int c4  = (idx & 15) * 4;
                xn[p] = *(const float4*)(x + (size_t)(rowbase + xr) * D_EMB + k0 + c4);
            }
#pragma unroll
            for (int p = 0; p < 4; ++p) {
                const int idx = p * 256 + tid;
                const int wr  = idx >> 3;
                const int off = (idx & 7) * 8;
                wn[p] = *(const bf16x8*)(wbf + (size_t)wr * D_EMB + k0 + off);
            }
        }

        // ---- compute chunk from LDS ----
#pragma unroll
        for (int s = 0; s < 2; ++s) {
            bf16x8 af[2];
#pragma unroll
            for (int mt = 0; mt < 2; ++mt)
                af[mt] = *(const bf16x8*)&xs[mt * 16 + col][s * 32 + quad * 8];
            bf16x8 bfr[2];
#pragma unroll
            for (int nt = 0; nt < 2; ++nt)
                bfr[nt] = *(const bf16x8*)&wsh[wave * 32 + nt * 16 + col][s * 32 + quad * 8];
#pragma unroll
            for (int mt = 0; mt < 2; ++mt)
#pragma unroll
                for (int nt = 0; nt < 2; ++nt)
                    acc[mt][nt] = __builtin_amdgcn_mfma_f32_16x16x32_bf16(
                        af[mt], bfr[nt], acc[mt][nt], 0, 0, 0);
        }
        __syncthreads();
    }

    // ---- epilogue: C layout col=lane&15, row=quad*4+reg ----
    // waves 0,1 own kmat cols 0..63; waves 2,3 own qvmat cols 0..63.
#pragma unroll
    for (int mt = 0; mt < 2; ++mt)
#pragma unroll
        for (int nt = 0; nt < 2; ++nt) {
            const int gcol = wave * 32 + nt * 16 + col;
#pragma unroll
            for (int r = 0; r < 4; ++r) {
                const int grow = rowbase + mt * 16 + quad * 4 + r;
                const int ltt  = mt * 16 + quad * 4 + r;
                bf16 bv = (bf16)acc[mt][nt][r];
                if (gcol < 64) {
                    kmat[(size_t)grow * HS + gcol] = bv;
                } else {
                    qvmat[(size_t)grow * HS + (gcol - 64)] = bv;
                    vt[gcol - 64][ltt] = bv;     // transpose tile in LDS
                }
            }
        }
    __syncthreads();

    // qvT store: thread -> (h = tid>>2, 8-elem segment), 16 B coalesced rows
    {
        const int h   = tid >> 2;
        const int seg = (tid & 3) * 8;
        bf16x8 v = *(const bf16x8*)&vt[h][seg];
        const int bb  = rowbase >> 12;
        const int tt0 = (rowbase & (T_SEQ - 1)) + seg;
        *(bf16x8*)(qvT + ((size_t)bb * HS + h) * T_SEQ + tt0) = v;
    }
}

// ---------------------------------------------------------------------------
// Kernel 2: staged-LDS causal attention, fixed-offset softmax, q = v.
// Single-buffered LDS (23.4 KB) + register prefetch across the chunk barrier.
// launch_bounds(256,4): 4 blocks/CU at VGPR<=128 (no spill). Heavy jobs
// dispatch first. Partial (O, l) per job slot; norm combines.
// ---------------------------------------------------------------------------
__global__ __launch_bounds__(256, 4) void attn_kernel(
    const bf16* __restrict__ kmat,   // [B*T][64]
    const bf16* __restrict__ qvmat,  // [B*T][64]
    const bf16* __restrict__ qvT,    // [B][64][T]
    float* __restrict__ out,         // [B*T][64] raw O partial, slot 0
    float* __restrict__ o_parts,     // [7][B*T][64] raw O partials, slots 1-7
    float* __restrict__ l_parts)     // [8][B*T] l partials
{
    __shared__ bf16 Kt[64][72];      // 9.2 KB
    __shared__ bf16 Vt[64][72];      // 9.2 KB
    __shared__ bf16 plds[4][16][40]; // 5 KB

    const int tid  = threadIdx.x;
    const int lane = tid & 63;
    const int wave = tid >> 6;
    const int col  = lane & 15;
    const int quad = lane >> 4;

    const int b = blockIdx.x / 288;
    const int r = 287 - (blockIdx.x - b * 288);   // heavy tiers first
    int a = 0;
    while (4 * (a + 1) * (a + 2) <= r) ++a;       // a in 0..7
    const int rr = r - 4 * a * (a + 1);
    const int m  = rr / (a + 1);
    const int jc = rr - m * (a + 1);              // job slot 0..a
    const int qb = 8 * a + m;                     // q-block 0..63

    const int cbeg  = jc * 8;
    const int nctot = qb + 1;
    const int cend  = (nctot < cbeg + 8) ? nctot : cbeg + 8;

    const bf16* qvb = qvmat + (size_t)b * T_SEQ * HS;
    const bf16* kb  = kmat  + (size_t)b * T_SEQ * HS;
    const bf16* vTb = qvT   + (size_t)b * HS * T_SEQ;

    const int q0 = qb * 64 + wave * 16;

    bf16x8 qf0 = *(const bf16x8*)(qvb + (size_t)(q0 + col) * HS + quad * 8);
    bf16x8 qf1 = *(const bf16x8*)(qvb + (size_t)(q0 + col) * HS + 32 + quad * 8);

    f32x4 o[4];
    float lp[4];
#pragma unroll
    for (int h = 0; h < 4; ++h) o[h] = {0.f, 0.f, 0.f, 0.f};
#pragma unroll
    for (int i = 0; i < 4; ++i) lp[i] = 0.f;

    const float sc = 0.125f * 1.44269504088896f;

    // register prefetch of first chunk
    bf16x8 kn[2], vn[2];
    {
        const int kc = cbeg * 64;
#pragma unroll
        for (int it = 0; it < 2; ++it) {
            const int idx = it * 256 + tid;
            const int kr  = idx >> 3;
            const int off = (idx & 7) * 8;
            kn[it] = *(const bf16x8*)(kb + (size_t)kc * HS + idx * 8);
            vn[it] = *(const bf16x8*)(vTb + (size_t)kr * T_SEQ + kc + off);
        }
    }

#pragma unroll 1
    for (int c = cbeg; c < cend; ++c) {
        // ---- write prefetched chunk into LDS ----
#pragma unroll
        for (int it = 0; it < 2; ++it) {
            const int idx = it * 256 + tid;
            const int kr  = idx >> 3;
            const int off = (idx & 7) * 8;
            *(bf16x8*)&Kt[kr][off] = kn[it];
            *(bf16x8*)&Vt[kr][off] = vn[it];
        }
        __syncthreads();

        // ---- issue next chunk's loads (hidden behind compute) ----
        if (c + 1 < cend) {
            const int kcn = (c + 1) * 64;
#pragma unroll
            for (int it = 0; it < 2; ++it) {
                const int idx = it * 256 + tid;
                const int kr  = idx >> 3;
                const int off = (idx & 7) * 8;
                kn[it] = *(const bf16x8*)(kb + (size_t)kcn * HS + idx * 8);
                vn[it] = *(const bf16x8*)(vTb + (size_t)kr * T_SEQ + kcn + off);
            }
        }

        // ---- compute chunk c from LDS ----
        const int kc = c * 64;
#pragma unroll
        for (int st = 0; st < 2; ++st) {
            const int gk = kc + 32 * st;
            if (gk > q0 + 15) break;             // fully masked (wave-uniform)

            bf16x8 b0 = *(const bf16x8*)&Kt[32 * st + col][quad * 8];
            bf16x8 b1 = *(const bf16x8*)&Kt[32 * st + col][32 + quad * 8];
            bf16x8 b2 = *(const bf16x8*)&Kt[32 * st + 16 + col][quad * 8];
            bf16x8 b3 = *(const bf16x8*)&Kt[32 * st + 16 + col][32 + quad * 8];

            float p[2][4];
            {
                f32x4 a4 = {0.f, 0.f, 0.f, 0.f};
                a4 = __builtin_amdgcn_mfma_f32_16x16x32_bf16(qf0, b0, a4, 0, 0, 0);
                a4 = __builtin_amdgcn_mfma_f32_16x16x32_bf16(qf1, b1, a4, 0, 0, 0);
#pragma unroll
                for (int i = 0; i < 4; ++i) p[0][i] = fexp2(fmaf(a4[i], sc, -24.f));
            }
            {
                f32x4 a4 = {0.f, 0.f, 0.f, 0.f};
                a4 = __builtin_amdgcn_mfma_f32_16x16x32_bf16(qf0, b2, a4, 0, 0, 0);
                a4 = __builtin_amdgcn_mfma_f32_16x16x32_bf16(qf1, b3, a4, 0, 0, 0);
#pragma unroll
                for (int i = 0; i < 4; ++i) p[1][i] = fexp2(fmaf(a4[i], sc, -24.f));
            }

            if (gk + 31 > q0) {                  // diagonal subtile: mask
#pragma unroll
                for (int nt = 0; nt < 2; ++nt)
#pragma unroll
                    for (int i = 0; i < 4; ++i)
                        if (gk + nt * 16 + col > q0 + quad * 4 + i)
                            p[nt][i] = 0.f;
            }

#pragma unroll
            for (int i = 0; i < 4; ++i) lp[i] += p[0][i] + p[1][i];

            // P: C-layout -> LDS -> A-layout (wave-private, in-order DS)
#pragma unroll
            for (int nt = 0; nt < 2; ++nt)
#pragma unroll
                for (int i = 0; i < 4; ++i)
                    plds[wave][quad * 4 + i][nt * 16 + col] = (bf16)p[nt][i];
            bf16x8 pa = *(const bf16x8*)&plds[wave][col][quad * 8];

#pragma unroll
            for (int h = 0; h < 4; ++h) {
                bf16x8 vb = *(const bf16x8*)&Vt[h * 16 + col][32 * st + quad * 8];
                o[h] = __builtin_amdgcn_mfma_f32_16x16x32_bf16(pa, vb, o[h], 0, 0, 0);
            }
        }
        __syncthreads();   // protect Kt/Vt before next write
    }

    // ---- epilogue: waves own disjoint rows -> direct partial stores ----
    float lr[4];
#pragma unroll
    for (int i = 0; i < 4; ++i) {
        float v = lp[i];
#pragma unroll
        for (int off = 1; off < 16; off <<= 1)
            v += __shfl_xor(v, off, 64);
        lr[i] = v;
    }

    const size_t rowbase = (size_t)b * T_SEQ + q0 + quad * 4;
    if (col == 0) {
#pragma unroll
        for (int i = 0; i < 4; ++i)
            l_parts[(size_t)jc * 16384 + rowbase + i] = lr[i];
    }

    float* dst = (jc == 0) ? out : (o_parts + (size_t)(jc - 1) * 16384 * HS);
#pragma unroll
    for (int h = 0; h < 4; ++h)
#pragma unroll
        for (int i = 0; i < 4; ++i)
            dst[(rowbase + i) * HS + h * 16 + col] = o[h][i];
}

// ---------------------------------------------------------------------------
// Kernel 3: combine job partials and normalize: out = sum(O_j) / sum(l_j).
// ---------------------------------------------------------------------------
__global__ __launch_bounds__(256) void norm_kernel(
    float* __restrict__ out,
    const float* __restrict__ o_parts,  // [7][B*T][64]
    const float* __restrict__ l_parts)  // [8][B*T]
{
    const int i   = blockIdx.x * 256 + threadIdx.x;
    const int row = i >> 6;
    const int qb  = (row & 4095) >> 6;
    const int nj  = (qb >> 3) + 1;

    float s = out[i];
    float L = l_parts[row];
    for (int j = 1; j < nj; ++j) {
        s += o_parts[(size_t)(j - 1) * 1048576 + i];
        L += l_parts[(size_t)j * 16384 + row];
    }
    out[i] = s / L;
}

extern "C" void kernel_launch(void* const* d_in, const int* in_sizes, int n_in,
                              void* d_out, int out_size, void* d_ws, size_t ws_size,
                              hipStream_t stream) {
    const float* x  = (const float*)d_in[0];
    const float* Wk = (const float*)d_in[1];
    const float* Wv = (const float*)d_in[2];
    float* out = (float*)d_out;

    bf16* ws    = (bf16*)d_ws;
    bf16* wbf   = ws;                                    // 256 KB
    bf16* kmat  = ws + (size_t)128 * 1024;               // 2 MB
    bf16* qvmat = kmat + (size_t)16384 * 64;             // 2 MB
    bf16* qvT   = qvmat + (size_t)16384 * 64;            // 2 MB
    float* o_parts = (float*)(qvT + (size_t)16384 * 64); // 28 MB (slots 1-7)
    float* l_parts = o_parts + (size_t)7 * 16384 * 64;   // 512 KB

    wcast_kernel<<<64, 256, 0, stream>>>(Wk, Wv, wbf);
    proj_kernel<<<512, 256, 0, stream>>>(x, wbf, kmat, qvmat, qvT);
    attn_kernel<<<1152, 256, 0, stream>>>(kmat, qvmat, qvT, out, o_parts, l_parts);
    norm_kernel<<<4096, 256, 0, stream>>>(out, o_parts, l_parts);
}